// Round 7
// baseline (487.757 us; speedup 1.0000x reference)
//
#include <hip/hip_runtime.h>
#include <hip/hip_bf16.h>

// InfoNCE: a[4096,512], p[4096,512], n[16384,512] f32 -> 4 f32 scalars.
// R7: NO-LDS, NO-BARRIER GEMM. Operands are L2-resident (a8=2MB < 4MB/XCD L2).
//     Each wave holds a 32-row B-tile in 64 VGPRs (loaded once) and sweeps
//     64-row m-tiles reading A fragments directly global->VGPR (b128 loads,
//     16 rows x 64B full sectors per instr). Zero __syncthreads -> no vmcnt(0)
//     drain convoy (the R4-R6 wall: MFMA busy was ~27us constant, rest stalls).
// ws layout: a8(2MB) p8(2MB) n8(8MB) | S[4096] csA[512*16] csP[512*16] csN[512*16] lsum[1]

#define D_DIM 512
#define B_ROWS 4096
#define P_ROWS 4096
#define N_ROWS 16384
#define INV_T 14.285714285714286f
#define EPS_L 1e-8f
#define CS_STRIDE 16

typedef unsigned char fp8_t;
typedef __attribute__((ext_vector_type(4))) float floatx4;   // MFMA C/D frag
typedef __attribute__((ext_vector_type(2))) long longx2;     // 16B = 2 MFMA operands
typedef unsigned int uint32;

// ---- fused: L2-normalize rows -> fp8 e4m3, and accumulate fp32 column sums ----
__global__ __launch_bounds__(256) void norm_colsum(
        const float* __restrict__ a, const float* __restrict__ p, const float* __restrict__ n,
        fp8_t* __restrict__ a8, fp8_t* __restrict__ p8, fp8_t* __restrict__ n8,
        float* __restrict__ csA, float* __restrict__ csP, float* __restrict__ csN) {
    const float* in; fp8_t* outp; float* cs; int rows, nb, bseg;
    int b = blockIdx.x;
    if (b < 256)      { in = a; outp = a8; cs = csA; rows = B_ROWS; nb = 256; bseg = b; }
    else if (b < 512) { in = p; outp = p8; cs = csP; rows = P_ROWS; nb = 256; bseg = b - 256; }
    else              { in = n; outp = n8; cs = csN; rows = N_ROWS; nb = 512; bseg = b - 512; }

    const int wave = threadIdx.x >> 6;
    const int lane = threadIdx.x & 63;

    float cs0[4] = {0.f, 0.f, 0.f, 0.f};
    float cs1[4] = {0.f, 0.f, 0.f, 0.f};

    for (int chunk = bseg; chunk < (rows >> 2); chunk += nb) {
        int r = chunk * 4 + wave;
        const float4* rp = reinterpret_cast<const float4*>(in + (size_t)r * D_DIM);
        float4 v0 = rp[lane];
        float4 v1 = rp[lane + 64];
        float ss = v0.x*v0.x + v0.y*v0.y + v0.z*v0.z + v0.w*v0.w
                 + v1.x*v1.x + v1.y*v1.y + v1.z*v1.z + v1.w*v1.w;
#pragma unroll
        for (int off = 1; off < 64; off <<= 1) ss += __shfl_xor(ss, off);
        float inv = 1.0f / fmaxf(sqrtf(ss), 1e-12f);
        float f0x = v0.x*inv, f0y = v0.y*inv, f0z = v0.z*inv, f0w = v0.w*inv;
        float f1x = v1.x*inv, f1y = v1.y*inv, f1z = v1.z*inv, f1w = v1.w*inv;
        cs0[0] += f0x; cs0[1] += f0y; cs0[2] += f0z; cs0[3] += f0w;
        cs1[0] += f1x; cs1[1] += f1y; cs1[2] += f1z; cs1[3] += f1w;
        int pk0 = __builtin_amdgcn_cvt_pk_fp8_f32(f0x, f0y, 0, 0);
        pk0     = __builtin_amdgcn_cvt_pk_fp8_f32(f0z, f0w, pk0, 1);
        int pk1 = __builtin_amdgcn_cvt_pk_fp8_f32(f1x, f1y, 0, 0);
        pk1     = __builtin_amdgcn_cvt_pk_fp8_f32(f1z, f1w, pk1, 1);
        uint32* op = reinterpret_cast<uint32*>(outp + (size_t)r * D_DIM);
        op[lane]      = (uint32)pk0;
        op[lane + 64] = (uint32)pk1;
    }

    __shared__ float csh[D_DIM];
    if (threadIdx.x < 256) { csh[threadIdx.x] = 0.f; csh[threadIdx.x + 256] = 0.f; }
    __syncthreads();
#pragma unroll
    for (int j = 0; j < 4; ++j) {
        atomicAdd(&csh[lane * 4 + j], cs0[j]);
        atomicAdd(&csh[256 + lane * 4 + j], cs1[j]);
    }
    __syncthreads();
    if (threadIdx.x < 256) {
        atomicAdd(&cs[(size_t)threadIdx.x * CS_STRIDE], csh[threadIdx.x]);
        atomicAdd(&cs[(size_t)(threadIdx.x + 256) * CS_STRIDE], csh[threadIdx.x + 256]);
    }
}

// ---------------- fp8 MFMA GEMM: L2-direct, no LDS, no barriers ----------------
// K-mapping (identical for A and B => dot exact): MFMA call (kb,t,half) for
// lane quad q consumes global cols [ (kb*8+t*4+q)*16 + half*8 , +8 ).
// Per-lane A/B frag for mfma_16x16x32_fp8: m(or n) = lane&15, k-slot = q*8+j.
// EPI==0: S[row] += sum_n exp(sim*invT)   EPI==1: loss_sum += -log(pe/(pe+S)+eps)
template <int EPI>
__global__ __launch_bounds__(256, 3) void gemm_epi(const fp8_t* __restrict__ A,
                                                   const fp8_t* __restrict__ Bm,
                                                   float* __restrict__ S,
                                                   float* __restrict__ loss_sum,
                                                   int mtiles) {
    const int lane = threadIdx.x & 63;
    const int w    = threadIdx.x >> 6;
    const int lr   = lane & 15;
    const int q    = lane >> 4;
    const int n0   = (blockIdx.x * 4 + w) * 32;   // wave-private 32-row B tile

    // ---- B resident in registers: 2ct x 4kb x 2t x 16B = 64 VGPRs ----
    longx2 Breg[2][4][2];
#pragma unroll
    for (int ct = 0; ct < 2; ++ct) {
        const fp8_t* brow = Bm + (size_t)(n0 + ct * 16 + lr) * D_DIM + q * 16;
#pragma unroll
        for (int kb = 0; kb < 4; ++kb)
#pragma unroll
            for (int t = 0; t < 2; ++t)
                Breg[ct][kb][t] = *reinterpret_cast<const longx2*>(brow + kb * 128 + t * 64);
    }

    float lsum = 0.f;
    const int m0base = blockIdx.y * mtiles * 64;

    for (int mi = 0; mi < mtiles; ++mi) {
        const int m0 = m0base + mi * 64;
        const fp8_t* abase = A + (size_t)(m0 + lr) * D_DIM + q * 16;

        floatx4 acc[4][2];
#pragma unroll
        for (int rt = 0; rt < 4; ++rt)
#pragma unroll
            for (int ct = 0; ct < 2; ++ct) acc[rt][ct] = (floatx4){0.f, 0.f, 0.f, 0.f};

#pragma unroll
        for (int rt = 0; rt < 4; ++rt) {
            // 8 independent b128 loads (16 rows x 64B full sectors per instr)
            longx2 av[4][2];
#pragma unroll
            for (int kb = 0; kb < 4; ++kb)
#pragma unroll
                for (int t = 0; t < 2; ++t)
                    av[kb][t] = *reinterpret_cast<const longx2*>(
                        abase + rt * 16 * D_DIM + kb * 128 + t * 64);
#pragma unroll
            for (int kb = 0; kb < 4; ++kb)
#pragma unroll
                for (int t = 0; t < 2; ++t) {
#pragma unroll
                    for (int ct = 0; ct < 2; ++ct)
                        acc[rt][ct] = __builtin_amdgcn_mfma_f32_16x16x32_fp8_fp8(
                            av[kb][t].x, Breg[ct][kb][t].x, acc[rt][ct], 0, 0, 0);
#pragma unroll
                    for (int ct = 0; ct < 2; ++ct)
                        acc[rt][ct] = __builtin_amdgcn_mfma_f32_16x16x32_fp8_fp8(
                            av[kb][t].y, Breg[ct][kb][t].y, acc[rt][ct], 0, 0, 0);
                }
        }

        // C/D layout: col(n within 16) = lane&15, row(m within 16) = q*4 + reg
        if (EPI == 0) {
#pragma unroll
            for (int rt = 0; rt < 4; ++rt) {
#pragma unroll
                for (int reg = 0; reg < 4; ++reg) {
                    float v = __expf(acc[rt][0][reg] * INV_T) + __expf(acc[rt][1][reg] * INV_T);
                    v += __shfl_xor(v, 1);
                    v += __shfl_xor(v, 2);
                    v += __shfl_xor(v, 4);
                    v += __shfl_xor(v, 8);
                    if (lr == 0) atomicAdd(&S[m0 + rt * 16 + q * 4 + reg], v);
                }
            }
        } else {
#pragma unroll
            for (int rt = 0; rt < 4; ++rt) {
#pragma unroll
                for (int reg = 0; reg < 4; ++reg) {
                    float Sv = S[m0 + rt * 16 + q * 4 + reg];
#pragma unroll
                    for (int ct = 0; ct < 2; ++ct) {
                        float pe = __expf(acc[rt][ct][reg] * INV_T);
                        lsum -= __logf(pe / (pe + Sv) + EPS_L);
                    }
                }
            }
        }
    }

    if (EPI == 1) {
#pragma unroll
        for (int off = 1; off < 64; off <<= 1) lsum += __shfl_xor(lsum, off);
        if (lane == 0) atomicAdd(loss_sum, lsum);
    }
}

// ---- finalize: dot the (strided) column sums, emit the 4 scalars ----
__global__ void finalize_k(const float* __restrict__ csA, const float* __restrict__ csP,
                           const float* __restrict__ csN, const float* __restrict__ lsum,
                           float* __restrict__ out) {
    int tid = threadIdx.x;  // 512
    float av = csA[(size_t)tid * CS_STRIDE];
    float dp = av * csP[(size_t)tid * CS_STRIDE];
    float dn = av * csN[(size_t)tid * CS_STRIDE];
#pragma unroll
    for (int off = 1; off < 64; off <<= 1) {
        dp += __shfl_xor(dp, off);
        dn += __shfl_xor(dn, off);
    }
    __shared__ float red[16];
    int wid = tid >> 6, lane = tid & 63;
    if (lane == 0) { red[wid] = dp; red[8 + wid] = dn; }
    __syncthreads();
    if (tid == 0) {
        float sdp = 0.f, sdn = 0.f;
#pragma unroll
        for (int i = 0; i < 8; ++i) { sdp += red[i]; sdn += red[8 + i]; }
        float mean_pos = sdp * INV_T / ((float)B_ROWS * (float)P_ROWS);
        float mean_neg = sdn * INV_T / ((float)B_ROWS * (float)N_ROWS);
        out[0] = lsum[0] / ((float)B_ROWS * (float)P_ROWS);
        out[1] = mean_pos;
        out[2] = mean_neg;
        out[3] = mean_pos - mean_neg;
    }
}

extern "C" void kernel_launch(void* const* d_in, const int* in_sizes, int n_in,
                              void* d_out, int out_size, void* d_ws, size_t ws_size,
                              hipStream_t stream) {
    const float* anc = (const float*)d_in[0];
    const float* pos = (const float*)d_in[1];
    const float* neg = (const float*)d_in[2];
    float* out = (float*)d_out;

    fp8_t* a8 = (fp8_t*)d_ws;
    fp8_t* p8 = a8 + (size_t)B_ROWS * D_DIM;
    fp8_t* n8 = p8 + (size_t)P_ROWS * D_DIM;
    float* fsec = (float*)(n8 + (size_t)N_ROWS * D_DIM);
    float* S    = fsec;
    float* csA  = S + B_ROWS;
    float* csP  = csA + D_DIM * CS_STRIDE;
    float* csN  = csP + D_DIM * CS_STRIDE;
    float* lsum = csN + D_DIM * CS_STRIDE;

    hipMemsetAsync(fsec, 0, (B_ROWS + 3 * D_DIM * CS_STRIDE + 1) * sizeof(float), stream);

    norm_colsum<<<1024, 256, 0, stream>>>(anc, pos, neg, a8, p8, n8, csA, csP, csN);

    // neg: x = 16384/(32*4) = 128 n-blocks; y = 16 m-chunks x mtiles=4 x 64 = 4096 rows
    gemm_epi<0><<<dim3(128, 16), 256, 0, stream>>>(a8, n8, S, nullptr, 4);
    // pos: x = 4096/(32*4) = 32; y = 16, mtiles=4
    gemm_epi<1><<<dim3(32, 16), 256, 0, stream>>>(a8, p8, S, lsum, 4);

    finalize_k<<<1, 512, 0, stream>>>(csA, csP, csN, lsum, out);
}

// Round 8
// 478.173 us; speedup vs baseline: 1.0200x; 1.0200x over previous
//
#include <hip/hip_runtime.h>
#include <hip/hip_bf16.h>

// InfoNCE: a[4096,512], p[4096,512], n[16384,512] f32 -> 4 f32 scalars.
// R8: R4 structure (proven best, 110us neg) with the inner loop ported to
//     MX-scaled fp8: mfma_scale_f32_32x32x64_f8f6f4, unit scales (E8M0 0x7F).
//     2x MFMA rate + 8x fewer MFMA instrs (m145->m148 measured 1.64x on this
//     exact structure). Staging/swizzle/grids/epilogue math unchanged from R4.
// ws layout: a8(2MB) p8(2MB) n8(8MB) | S[4096] csA[512*16] csP[512*16] csN[512*16] lsum[1]

#define D_DIM 512
#define B_ROWS 4096
#define P_ROWS 4096
#define N_ROWS 16384
#define INV_T 14.285714285714286f
#define EPS_L 1e-8f
#define CS_STRIDE 16

typedef unsigned char fp8_t;
typedef __attribute__((ext_vector_type(4))) int int4v;      // 16B LDS read
typedef __attribute__((ext_vector_type(8))) int int8v;      // MFMA A/B frag (32B)
typedef __attribute__((ext_vector_type(16))) float floatx16; // MFMA C/D frag (32x32)
typedef unsigned int uint32;

// ---- fused: L2-normalize rows -> fp8 e4m3, and accumulate fp32 column sums ----
__global__ __launch_bounds__(256) void norm_colsum(
        const float* __restrict__ a, const float* __restrict__ p, const float* __restrict__ n,
        fp8_t* __restrict__ a8, fp8_t* __restrict__ p8, fp8_t* __restrict__ n8,
        float* __restrict__ csA, float* __restrict__ csP, float* __restrict__ csN) {
    const float* in; fp8_t* outp; float* cs; int rows, nb, bseg;
    int b = blockIdx.x;
    if (b < 256)      { in = a; outp = a8; cs = csA; rows = B_ROWS; nb = 256; bseg = b; }
    else if (b < 512) { in = p; outp = p8; cs = csP; rows = P_ROWS; nb = 256; bseg = b - 256; }
    else              { in = n; outp = n8; cs = csN; rows = N_ROWS; nb = 512; bseg = b - 512; }

    const int wave = threadIdx.x >> 6;
    const int lane = threadIdx.x & 63;

    float cs0[4] = {0.f, 0.f, 0.f, 0.f};
    float cs1[4] = {0.f, 0.f, 0.f, 0.f};

    for (int chunk = bseg; chunk < (rows >> 2); chunk += nb) {
        int r = chunk * 4 + wave;
        const float4* rp = reinterpret_cast<const float4*>(in + (size_t)r * D_DIM);
        float4 v0 = rp[lane];
        float4 v1 = rp[lane + 64];
        float ss = v0.x*v0.x + v0.y*v0.y + v0.z*v0.z + v0.w*v0.w
                 + v1.x*v1.x + v1.y*v1.y + v1.z*v1.z + v1.w*v1.w;
#pragma unroll
        for (int off = 1; off < 64; off <<= 1) ss += __shfl_xor(ss, off);
        float inv = 1.0f / fmaxf(sqrtf(ss), 1e-12f);
        float f0x = v0.x*inv, f0y = v0.y*inv, f0z = v0.z*inv, f0w = v0.w*inv;
        float f1x = v1.x*inv, f1y = v1.y*inv, f1z = v1.z*inv, f1w = v1.w*inv;
        cs0[0] += f0x; cs0[1] += f0y; cs0[2] += f0z; cs0[3] += f0w;
        cs1[0] += f1x; cs1[1] += f1y; cs1[2] += f1z; cs1[3] += f1w;
        int pk0 = __builtin_amdgcn_cvt_pk_fp8_f32(f0x, f0y, 0, 0);
        pk0     = __builtin_amdgcn_cvt_pk_fp8_f32(f0z, f0w, pk0, 1);
        int pk1 = __builtin_amdgcn_cvt_pk_fp8_f32(f1x, f1y, 0, 0);
        pk1     = __builtin_amdgcn_cvt_pk_fp8_f32(f1z, f1w, pk1, 1);
        uint32* op = reinterpret_cast<uint32*>(outp + (size_t)r * D_DIM);
        op[lane]      = (uint32)pk0;
        op[lane + 64] = (uint32)pk1;
    }

    __shared__ float csh[D_DIM];
    if (threadIdx.x < 256) { csh[threadIdx.x] = 0.f; csh[threadIdx.x + 256] = 0.f; }
    __syncthreads();
#pragma unroll
    for (int j = 0; j < 4; ++j) {
        atomicAdd(&csh[lane * 4 + j], cs0[j]);
        atomicAdd(&csh[256 + lane * 4 + j], cs1[j]);
    }
    __syncthreads();
    if (threadIdx.x < 256) {
        atomicAdd(&cs[(size_t)threadIdx.x * CS_STRIDE], csh[threadIdx.x]);
        atomicAdd(&cs[(size_t)(threadIdx.x + 256) * CS_STRIDE], csh[threadIdx.x + 256]);
    }
}

// ---------------- MX-fp8 MFMA GEMM with fused epilogue ----------------
#define BM 128
#define BN 128
#define BKB 128  // K-elements (bytes) per staged tile

typedef const __attribute__((address_space(1))) unsigned int* as1_u32p;
typedef __attribute__((address_space(3))) unsigned int* as3_u32p;

__device__ __forceinline__ void load_lds16(const void* g, void* l) {
    // each lane writes 16B at (wave-uniform l) + lane*16
    __builtin_amdgcn_global_load_lds((as1_u32p)g, (as3_u32p)l, 16, 0, 0);
}

#define SCALE1 0x7F7F7F7F  // E8M0 127 = 1.0 in every byte

// EPI==0: C = A@Bm^T, S[row] += sum_col exp(C*invT)           (neg pass)
// EPI==1: loss_sum += sum(-log(exp(C*invT)/(exp+S[row])+eps)) (pos pass)
template <int EPI>
__global__ __launch_bounds__(256, 4) void gemm_epi(const fp8_t* __restrict__ A,
                                                   const fp8_t* __restrict__ Bm,
                                                   float* __restrict__ S,
                                                   float* __restrict__ loss_sum) {
    __shared__ fp8_t As[BM * BKB];  // 16 KB, XOR-swizzled 16B granules
    __shared__ fp8_t Bs[BN * BKB];  // 16 KB

    const int tid  = threadIdx.x;
    const int lane = tid & 63;
    const int w    = tid >> 6;          // wave 0..3
    const int wm   = w >> 1, wn = w & 1;
    const int m0   = blockIdx.y * BM;
    const int n0   = blockIdx.x * BN;
    const int l31  = lane & 31;         // row within 32-tile
    const int kh   = lane >> 5;         // k-half selector (32B of 64)
    const int x7   = l31 & 7;           // swizzle term for gathers

    floatx16 acc[2][2];
#pragma unroll
    for (int i = 0; i < 2; ++i)
#pragma unroll
        for (int j = 0; j < 2; ++j)
#pragma unroll
            for (int e = 0; e < 16; ++e) acc[i][j][e] = 0.f;

    // staging (unchanged from R4): lane fetches row rbase+(lane>>3), logical
    // granule (lane&7)^(lane>>3) -> logical granule g of row r lands at slot
    // g^(r&7). One instr = 8 rows x 128B.
    const int srow   = lane >> 3;
    const int schunk = (lane & 7) ^ srow;

    for (int kt = 0; kt < D_DIM; kt += BKB) {
        __syncthreads();  // prior ds_reads done before overwrite
#pragma unroll
        for (int i = 0; i < 4; ++i) {
            int rbase = w * 32 + i * 8;
            const fp8_t* asrc = A + (size_t)(m0 + rbase + srow) * D_DIM + kt + schunk * 16;
            load_lds16(asrc, &As[rbase * BKB]);
            const fp8_t* bsrc = Bm + (size_t)(n0 + rbase + srow) * D_DIM + kt + schunk * 16;
            load_lds16(bsrc, &Bs[rbase * BKB]);
        }
        __syncthreads();  // staging drained

        // Two K=64 steps per staged tile. Lane's 32B operand = logical granules
        // {g0, g0+1}, g0 = s*4 + kh*2. Same (lane->k) map for A and B => exact.
#pragma unroll
        for (int s = 0; s < 2; ++s) {
            const int g0 = s * 4 + kh * 2;
            int8v af[2], bf[2];
#pragma unroll
            for (int mt = 0; mt < 2; ++mt) {
                int rb = (wm * 64 + mt * 32 + l31) * BKB;
                int4v lo = *reinterpret_cast<const int4v*>(&As[rb + ((g0 ^ x7) << 4)]);
                int4v hi = *reinterpret_cast<const int4v*>(&As[rb + (((g0 + 1) ^ x7) << 4)]);
                af[mt] = __builtin_shufflevector(lo, hi, 0, 1, 2, 3, 4, 5, 6, 7);
            }
#pragma unroll
            for (int nt = 0; nt < 2; ++nt) {
                int rb = (wn * 64 + nt * 32 + l31) * BKB;
                int4v lo = *reinterpret_cast<const int4v*>(&Bs[rb + ((g0 ^ x7) << 4)]);
                int4v hi = *reinterpret_cast<const int4v*>(&Bs[rb + (((g0 + 1) ^ x7) << 4)]);
                bf[nt] = __builtin_shufflevector(lo, hi, 0, 1, 2, 3, 4, 5, 6, 7);
            }
#pragma unroll
            for (int mt = 0; mt < 2; ++mt)
#pragma unroll
                for (int nt = 0; nt < 2; ++nt)
                    acc[mt][nt] = __builtin_amdgcn_mfma_scale_f32_32x32x64_f8f6f4(
                        af[mt], bf[nt], acc[mt][nt], 0, 0, 0, SCALE1, 0, SCALE1);
        }
    }

    // C/D layout (32x32): col = lane&31, row = (reg&3) + 8*(reg>>2) + 4*(lane>>5)
    if (EPI == 0) {
#pragma unroll
        for (int mt = 0; mt < 2; ++mt) {
#pragma unroll
            for (int reg = 0; reg < 16; ++reg) {
                float v = __expf(acc[mt][0][reg] * INV_T) + __expf(acc[mt][1][reg] * INV_T);
                v += __shfl_xor(v, 1);
                v += __shfl_xor(v, 2);
                v += __shfl_xor(v, 4);
                v += __shfl_xor(v, 8);
                v += __shfl_xor(v, 16);
                if (l31 == 0) {
                    int row = m0 + wm * 64 + mt * 32 + (reg & 3) + 8 * (reg >> 2) + 4 * kh;
                    atomicAdd(&S[row], v);
                }
            }
        }
    } else {
        float lsum = 0.f;
#pragma unroll
        for (int mt = 0; mt < 2; ++mt) {
#pragma unroll
            for (int reg = 0; reg < 16; ++reg) {
                int row = m0 + wm * 64 + mt * 32 + (reg & 3) + 8 * (reg >> 2) + 4 * kh;
                float Sv = S[row];
#pragma unroll
                for (int nt = 0; nt < 2; ++nt) {
                    float pe = __expf(acc[mt][nt][reg] * INV_T);
                    lsum -= __logf(pe / (pe + Sv) + EPS_L);
                }
            }
        }
#pragma unroll
        for (int off = 1; off < 64; off <<= 1) lsum += __shfl_xor(lsum, off);
        if (lane == 0) atomicAdd(loss_sum, lsum);
    }
}

// ---- finalize: dot the (strided) column sums, emit the 4 scalars ----
__global__ void finalize_k(const float* __restrict__ csA, const float* __restrict__ csP,
                           const float* __restrict__ csN, const float* __restrict__ lsum,
                           float* __restrict__ out) {
    int tid = threadIdx.x;  // 512
    float av = csA[(size_t)tid * CS_STRIDE];
    float dp = av * csP[(size_t)tid * CS_STRIDE];
    float dn = av * csN[(size_t)tid * CS_STRIDE];
#pragma unroll
    for (int off = 1; off < 64; off <<= 1) {
        dp += __shfl_xor(dp, off);
        dn += __shfl_xor(dn, off);
    }
    __shared__ float red[16];
    int wid = tid >> 6, lane = tid & 63;
    if (lane == 0) { red[wid] = dp; red[8 + wid] = dn; }
    __syncthreads();
    if (tid == 0) {
        float sdp = 0.f, sdn = 0.f;
#pragma unroll
        for (int i = 0; i < 8; ++i) { sdp += red[i]; sdn += red[8 + i]; }
        float mean_pos = sdp * INV_T / ((float)B_ROWS * (float)P_ROWS);
        float mean_neg = sdn * INV_T / ((float)B_ROWS * (float)N_ROWS);
        out[0] = lsum[0] / ((float)B_ROWS * (float)P_ROWS);
        out[1] = mean_pos;
        out[2] = mean_neg;
        out[3] = mean_pos - mean_neg;
    }
}

extern "C" void kernel_launch(void* const* d_in, const int* in_sizes, int n_in,
                              void* d_out, int out_size, void* d_ws, size_t ws_size,
                              hipStream_t stream) {
    const float* anc = (const float*)d_in[0];
    const float* pos = (const float*)d_in[1];
    const float* neg = (const float*)d_in[2];
    float* out = (float*)d_out;

    fp8_t* a8 = (fp8_t*)d_ws;
    fp8_t* p8 = a8 + (size_t)B_ROWS * D_DIM;
    fp8_t* n8 = p8 + (size_t)P_ROWS * D_DIM;
    float* fsec = (float*)(n8 + (size_t)N_ROWS * D_DIM);
    float* S    = fsec;
    float* csA  = S + B_ROWS;
    float* csP  = csA + D_DIM * CS_STRIDE;
    float* csN  = csP + D_DIM * CS_STRIDE;
    float* lsum = csN + D_DIM * CS_STRIDE;

    hipMemsetAsync(fsec, 0, (B_ROWS + 3 * D_DIM * CS_STRIDE + 1) * sizeof(float), stream);

    norm_colsum<<<1024, 256, 0, stream>>>(anc, pos, neg, a8, p8, n8, csA, csP, csN);

    gemm_epi<0><<<dim3(N_ROWS / BN, B_ROWS / BM), 256, 0, stream>>>(a8, n8, S, nullptr);
    gemm_epi<1><<<dim3(P_ROWS / BN, B_ROWS / BM), 256, 0, stream>>>(a8, p8, S, lsum);

    finalize_k<<<1, 512, 0, stream>>>(csA, csP, csN, lsum, out);
}

// Round 9
// 442.570 us; speedup vs baseline: 1.1021x; 1.0804x over previous
//
#include <hip/hip_runtime.h>
#include <hip/hip_bf16.h>

// InfoNCE: a[4096,512], p[4096,512], n[16384,512] f32 -> 4 f32 scalars.
// R9: R8 (MX-scaled fp8 32x32x64, mapping VERIFIED correct by R8's absmax=0)
//     with the register cap released: __launch_bounds__(256,3) -> ~170 VGPRs,
//     no accumulator spill (R8's (256,4)=128-cap spilled acc -> 348MB FETCH).
// ws layout: a8(2MB) p8(2MB) n8(8MB) | S[4096] csA[512*16] csP[512*16] csN[512*16] lsum[1]

#define D_DIM 512
#define B_ROWS 4096
#define P_ROWS 4096
#define N_ROWS 16384
#define INV_T 14.285714285714286f
#define EPS_L 1e-8f
#define CS_STRIDE 16

typedef unsigned char fp8_t;
typedef __attribute__((ext_vector_type(4))) int int4v;      // 16B LDS read
typedef __attribute__((ext_vector_type(8))) int int8v;      // MFMA A/B frag (32B)
typedef __attribute__((ext_vector_type(16))) float floatx16; // MFMA C/D frag (32x32)
typedef unsigned int uint32;

// ---- fused: L2-normalize rows -> fp8 e4m3, and accumulate fp32 column sums ----
__global__ __launch_bounds__(256) void norm_colsum(
        const float* __restrict__ a, const float* __restrict__ p, const float* __restrict__ n,
        fp8_t* __restrict__ a8, fp8_t* __restrict__ p8, fp8_t* __restrict__ n8,
        float* __restrict__ csA, float* __restrict__ csP, float* __restrict__ csN) {
    const float* in; fp8_t* outp; float* cs; int rows, nb, bseg;
    int b = blockIdx.x;
    if (b < 256)      { in = a; outp = a8; cs = csA; rows = B_ROWS; nb = 256; bseg = b; }
    else if (b < 512) { in = p; outp = p8; cs = csP; rows = P_ROWS; nb = 256; bseg = b - 256; }
    else              { in = n; outp = n8; cs = csN; rows = N_ROWS; nb = 512; bseg = b - 512; }

    const int wave = threadIdx.x >> 6;
    const int lane = threadIdx.x & 63;

    float cs0[4] = {0.f, 0.f, 0.f, 0.f};
    float cs1[4] = {0.f, 0.f, 0.f, 0.f};

    for (int chunk = bseg; chunk < (rows >> 2); chunk += nb) {
        int r = chunk * 4 + wave;
        const float4* rp = reinterpret_cast<const float4*>(in + (size_t)r * D_DIM);
        float4 v0 = rp[lane];
        float4 v1 = rp[lane + 64];
        float ss = v0.x*v0.x + v0.y*v0.y + v0.z*v0.z + v0.w*v0.w
                 + v1.x*v1.x + v1.y*v1.y + v1.z*v1.z + v1.w*v1.w;
#pragma unroll
        for (int off = 1; off < 64; off <<= 1) ss += __shfl_xor(ss, off);
        float inv = 1.0f / fmaxf(sqrtf(ss), 1e-12f);
        float f0x = v0.x*inv, f0y = v0.y*inv, f0z = v0.z*inv, f0w = v0.w*inv;
        float f1x = v1.x*inv, f1y = v1.y*inv, f1z = v1.z*inv, f1w = v1.w*inv;
        cs0[0] += f0x; cs0[1] += f0y; cs0[2] += f0z; cs0[3] += f0w;
        cs1[0] += f1x; cs1[1] += f1y; cs1[2] += f1z; cs1[3] += f1w;
        int pk0 = __builtin_amdgcn_cvt_pk_fp8_f32(f0x, f0y, 0, 0);
        pk0     = __builtin_amdgcn_cvt_pk_fp8_f32(f0z, f0w, pk0, 1);
        int pk1 = __builtin_amdgcn_cvt_pk_fp8_f32(f1x, f1y, 0, 0);
        pk1     = __builtin_amdgcn_cvt_pk_fp8_f32(f1z, f1w, pk1, 1);
        uint32* op = reinterpret_cast<uint32*>(outp + (size_t)r * D_DIM);
        op[lane]      = (uint32)pk0;
        op[lane + 64] = (uint32)pk1;
    }

    __shared__ float csh[D_DIM];
    if (threadIdx.x < 256) { csh[threadIdx.x] = 0.f; csh[threadIdx.x + 256] = 0.f; }
    __syncthreads();
#pragma unroll
    for (int j = 0; j < 4; ++j) {
        atomicAdd(&csh[lane * 4 + j], cs0[j]);
        atomicAdd(&csh[256 + lane * 4 + j], cs1[j]);
    }
    __syncthreads();
    if (threadIdx.x < 256) {
        atomicAdd(&cs[(size_t)threadIdx.x * CS_STRIDE], csh[threadIdx.x]);
        atomicAdd(&cs[(size_t)(threadIdx.x + 256) * CS_STRIDE], csh[threadIdx.x + 256]);
    }
}

// ---------------- MX-fp8 MFMA GEMM with fused epilogue ----------------
#define BM 128
#define BN 128
#define BKB 128  // K-elements (bytes) per staged tile

typedef const __attribute__((address_space(1))) unsigned int* as1_u32p;
typedef __attribute__((address_space(3))) unsigned int* as3_u32p;

__device__ __forceinline__ void load_lds16(const void* g, void* l) {
    // each lane writes 16B at (wave-uniform l) + lane*16
    __builtin_amdgcn_global_load_lds((as1_u32p)g, (as3_u32p)l, 16, 0, 0);
}

#define SCALE1 0x7F7F7F7F  // E8M0 127 = 1.0 in every byte

// EPI==0: C = A@Bm^T, S[row] += sum_col exp(C*invT)           (neg pass)
// EPI==1: loss_sum += sum(-log(exp(C*invT)/(exp+S[row])+eps)) (pos pass)
template <int EPI>
__global__ __launch_bounds__(256, 3) void gemm_epi(const fp8_t* __restrict__ A,
                                                   const fp8_t* __restrict__ Bm,
                                                   float* __restrict__ S,
                                                   float* __restrict__ loss_sum) {
    __shared__ fp8_t As[BM * BKB];  // 16 KB, XOR-swizzled 16B granules
    __shared__ fp8_t Bs[BN * BKB];  // 16 KB

    const int tid  = threadIdx.x;
    const int lane = tid & 63;
    const int w    = tid >> 6;          // wave 0..3
    const int wm   = w >> 1, wn = w & 1;
    const int m0   = blockIdx.y * BM;
    const int n0   = blockIdx.x * BN;
    const int l31  = lane & 31;         // row within 32-tile
    const int kh   = lane >> 5;         // k-half selector (32B of 64)
    const int x7   = l31 & 7;           // swizzle term for gathers

    floatx16 acc[2][2];
#pragma unroll
    for (int i = 0; i < 2; ++i)
#pragma unroll
        for (int j = 0; j < 2; ++j)
#pragma unroll
            for (int e = 0; e < 16; ++e) acc[i][j][e] = 0.f;

    // staging (R4-proven): lane fetches row rbase+(lane>>3), logical granule
    // (lane&7)^(lane>>3) -> logical granule g of row r lands at slot g^(r&7).
    const int srow   = lane >> 3;
    const int schunk = (lane & 7) ^ srow;

    for (int kt = 0; kt < D_DIM; kt += BKB) {
        __syncthreads();  // prior ds_reads done before overwrite
#pragma unroll
        for (int i = 0; i < 4; ++i) {
            int rbase = w * 32 + i * 8;
            const fp8_t* asrc = A + (size_t)(m0 + rbase + srow) * D_DIM + kt + schunk * 16;
            load_lds16(asrc, &As[rbase * BKB]);
            const fp8_t* bsrc = Bm + (size_t)(n0 + rbase + srow) * D_DIM + kt + schunk * 16;
            load_lds16(bsrc, &Bs[rbase * BKB]);
        }
        __syncthreads();  // staging drained

        // Two K=64 steps per staged tile. Lane's 32B operand = logical granules
        // {g0, g0+1}, g0 = s*4 + kh*2. Same (lane->k) map for A and B => exact.
#pragma unroll
        for (int s = 0; s < 2; ++s) {
            const int g0 = s * 4 + kh * 2;
            const int o0 = (g0 ^ x7) << 4;
            const int o1 = ((g0 + 1) ^ x7) << 4;
            int8v af[2], bf[2];
#pragma unroll
            for (int mt = 0; mt < 2; ++mt) {
                int rb = (wm * 64 + mt * 32 + l31) * BKB;
                int4v lo = *reinterpret_cast<const int4v*>(&As[rb + o0]);
                int4v hi = *reinterpret_cast<const int4v*>(&As[rb + o1]);
                af[mt] = __builtin_shufflevector(lo, hi, 0, 1, 2, 3, 4, 5, 6, 7);
            }
#pragma unroll
            for (int nt = 0; nt < 2; ++nt) {
                int rb = (wn * 64 + nt * 32 + l31) * BKB;
                int4v lo = *reinterpret_cast<const int4v*>(&Bs[rb + o0]);
                int4v hi = *reinterpret_cast<const int4v*>(&Bs[rb + o1]);
                bf[nt] = __builtin_shufflevector(lo, hi, 0, 1, 2, 3, 4, 5, 6, 7);
            }
#pragma unroll
            for (int mt = 0; mt < 2; ++mt)
#pragma unroll
                for (int nt = 0; nt < 2; ++nt)
                    acc[mt][nt] = __builtin_amdgcn_mfma_scale_f32_32x32x64_f8f6f4(
                        af[mt], bf[nt], acc[mt][nt], 0, 0, 0, SCALE1, 0, SCALE1);
        }
    }

    // C/D layout (32x32): col = lane&31, row = (reg&3) + 8*(reg>>2) + 4*(lane>>5)
    if (EPI == 0) {
#pragma unroll
        for (int mt = 0; mt < 2; ++mt) {
#pragma unroll
            for (int reg = 0; reg < 16; ++reg) {
                float v = __expf(acc[mt][0][reg] * INV_T) + __expf(acc[mt][1][reg] * INV_T);
                v += __shfl_xor(v, 1);
                v += __shfl_xor(v, 2);
                v += __shfl_xor(v, 4);
                v += __shfl_xor(v, 8);
                v += __shfl_xor(v, 16);
                if (l31 == 0) {
                    int row = m0 + wm * 64 + mt * 32 + (reg & 3) + 8 * (reg >> 2) + 4 * kh;
                    atomicAdd(&S[row], v);
                }
            }
        }
    } else {
        float lsum = 0.f;
#pragma unroll
        for (int mt = 0; mt < 2; ++mt) {
#pragma unroll
            for (int reg = 0; reg < 16; ++reg) {
                int row = m0 + wm * 64 + mt * 32 + (reg & 3) + 8 * (reg >> 2) + 4 * kh;
                float Sv = S[row];
#pragma unroll
                for (int nt = 0; nt < 2; ++nt) {
                    float pe = __expf(acc[mt][nt][reg] * INV_T);
                    lsum -= __logf(pe / (pe + Sv) + EPS_L);
                }
            }
        }
#pragma unroll
        for (int off = 1; off < 64; off <<= 1) lsum += __shfl_xor(lsum, off);
        if (lane == 0) atomicAdd(loss_sum, lsum);
    }
}

// ---- finalize: dot the (strided) column sums, emit the 4 scalars ----
__global__ void finalize_k(const float* __restrict__ csA, const float* __restrict__ csP,
                           const float* __restrict__ csN, const float* __restrict__ lsum,
                           float* __restrict__ out) {
    int tid = threadIdx.x;  // 512
    float av = csA[(size_t)tid * CS_STRIDE];
    float dp = av * csP[(size_t)tid * CS_STRIDE];
    float dn = av * csN[(size_t)tid * CS_STRIDE];
#pragma unroll
    for (int off = 1; off < 64; off <<= 1) {
        dp += __shfl_xor(dp, off);
        dn += __shfl_xor(dn, off);
    }
    __shared__ float red[16];
    int wid = tid >> 6, lane = tid & 63;
    if (lane == 0) { red[wid] = dp; red[8 + wid] = dn; }
    __syncthreads();
    if (tid == 0) {
        float sdp = 0.f, sdn = 0.f;
#pragma unroll
        for (int i = 0; i < 8; ++i) { sdp += red[i]; sdn += red[8 + i]; }
        float mean_pos = sdp * INV_T / ((float)B_ROWS * (float)P_ROWS);
        float mean_neg = sdn * INV_T / ((float)B_ROWS * (float)N_ROWS);
        out[0] = lsum[0] / ((float)B_ROWS * (float)P_ROWS);
        out[1] = mean_pos;
        out[2] = mean_neg;
        out[3] = mean_pos - mean_neg;
    }
}

extern "C" void kernel_launch(void* const* d_in, const int* in_sizes, int n_in,
                              void* d_out, int out_size, void* d_ws, size_t ws_size,
                              hipStream_t stream) {
    const float* anc = (const float*)d_in[0];
    const float* pos = (const float*)d_in[1];
    const float* neg = (const float*)d_in[2];
    float* out = (float*)d_out;

    fp8_t* a8 = (fp8_t*)d_ws;
    fp8_t* p8 = a8 + (size_t)B_ROWS * D_DIM;
    fp8_t* n8 = p8 + (size_t)P_ROWS * D_DIM;
    float* fsec = (float*)(n8 + (size_t)N_ROWS * D_DIM);
    float* S    = fsec;
    float* csA  = S + B_ROWS;
    float* csP  = csA + D_DIM * CS_STRIDE;
    float* csN  = csP + D_DIM * CS_STRIDE;
    float* lsum = csN + D_DIM * CS_STRIDE;

    hipMemsetAsync(fsec, 0, (B_ROWS + 3 * D_DIM * CS_STRIDE + 1) * sizeof(float), stream);

    norm_colsum<<<1024, 256, 0, stream>>>(anc, pos, neg, a8, p8, n8, csA, csP, csN);

    gemm_epi<0><<<dim3(N_ROWS / BN, B_ROWS / BM), 256, 0, stream>>>(a8, n8, S, nullptr);
    gemm_epi<1><<<dim3(P_ROWS / BN, B_ROWS / BM), 256, 0, stream>>>(a8, p8, S, lsum);

    finalize_k<<<1, 512, 0, stream>>>(csA, csP, csN, lsum, out);
}